// Round 8
// baseline (284.843 us; speedup 1.0000x reference)
//
#include <hip/hip_runtime.h>
#include <math.h>

// (B, N, D) = (16, 2048, 128)
constexpr int Bc = 16;
constexpr int Nc = 2048;
constexpr int Dc = 128;
constexpr int NCHUNK = Nc / 64;          // 32 key-chunks of 64
constexpr float SCALE_F = 0.08838834764831845f;  // 1/sqrt(128)

typedef __bf16 bf16x8 __attribute__((ext_vector_type(8)));
typedef __bf16 bf16x4 __attribute__((ext_vector_type(4)));
typedef float  f32x4  __attribute__((ext_vector_type(4)));

// ws layout: Kpack 8MB | Vpack 8MB | bias_packed 8.65MB | partials 44.7MB
constexpr size_t KPACK_BYTES = (size_t)Bc * NCHUNK * 16 * 64 * 16;
constexpr size_t VPACK_BYTES = KPACK_BYTES;
constexpr int NUNITS = 1056;             // bias units: sum_t C(t), t32 in [0,64)
constexpr size_t BIASP_BYTES = (size_t)NUNITS * 2048 * 4;
constexpr int CHUNK_ELEMS = 16 * 64 * 8; // 8192 bf16 = 16KB per chunk
// 128-row-tile partials: 42 partial units per b, each 128x128 O + m[128] + l[128]
constexpr int PART_FLOATS8 = 128 * 128 + 128 + 128;   // 16640
constexpr int NPART8 = 42;
constexpr size_t PART_BYTES8 = (size_t)Bc * NPART8 * PART_FLOATS8 * 4;

// ---- 8-wave persistent schedule ----
// Per b: 16 tiles of 128 rows; tile T has 2T+2 chunks (272 total), sliced into
// 44 contiguous units packed into 32 slots: slots 0-15 run 9 chunks, 16-31 run
// 8. Co-resident CU pair (s, s+16) sums to exactly 17 chunks. Units 42,43
// (tiles T1, T0) are single-slice -> direct write; units 0-41 write partials.
__device__ __constant__ signed char ST_T[32][3] = {
 {15,-1,-1},{15,-1,-1},{15,-1,-1},{15,14,-1},
 {14,-1,-1},{14,-1,-1},{14,13,-1},{13,-1,-1},
 {13,-1,-1},{13,-1,-1},{12,-1,-1},{12,-1,-1},
 {12,11,-1},{11,-1,-1},{11,-1,-1},{11,10,-1},
 {10,-1,-1},{10,-1,-1},{10, 9,-1},{ 9,-1,-1},
 { 9, 8,-1},{ 8,-1,-1},{ 8,-1,-1},{ 7,-1,-1},
 { 7,-1,-1},{ 6,-1,-1},{ 6, 5,-1},{ 5,-1,-1},
 { 5, 4,-1},{ 4, 3,-1},{ 3, 2,-1},{ 2, 1, 0}
};
__device__ __constant__ signed char ST_C0[32][3] = {
 { 0, 0, 0},{ 9, 0, 0},{18, 0, 0},{27, 0, 0},
 { 4, 0, 0},{13, 0, 0},{22, 0, 0},{ 1, 0, 0},
 {10, 0, 0},{19, 0, 0},{ 0, 0, 0},{ 9, 0, 0},
 {18, 0, 0},{ 1, 0, 0},{10, 0, 0},{19, 0, 0},
 { 4, 0, 0},{12, 0, 0},{20, 0, 0},{ 6, 0, 0},
 {14, 0, 0},{ 2, 0, 0},{10, 0, 0},{ 0, 0, 0},
 { 8, 0, 0},{ 0, 0, 0},{ 8, 0, 0},{ 2, 0, 0},
 {10, 0, 0},{ 6, 0, 0},{ 4, 0, 0},{ 4, 0, 0}
};
__device__ __constant__ signed char ST_C1[32][3] = {
 { 9, 0, 0},{18, 0, 0},{27, 0, 0},{32, 4, 0},
 {13, 0, 0},{22, 0, 0},{30, 1, 0},{10, 0, 0},
 {19, 0, 0},{28, 0, 0},{ 9, 0, 0},{18, 0, 0},
 {26, 1, 0},{10, 0, 0},{19, 0, 0},{24, 4, 0},
 {12, 0, 0},{20, 0, 0},{22, 6, 0},{14, 0, 0},
 {20, 2, 0},{10, 0, 0},{18, 0, 0},{ 8, 0, 0},
 {16, 0, 0},{ 8, 0, 0},{14, 2, 0},{10, 0, 0},
 {12, 6, 0},{10, 4, 0},{ 8, 4, 0},{ 6, 4, 2}
};
__device__ __constant__ signed char ST_U[32][3] = {
 { 0,-1,-1},{ 1,-1,-1},{ 2,-1,-1},{ 3, 4,-1},
 { 5,-1,-1},{ 6,-1,-1},{ 7, 8,-1},{ 9,-1,-1},
 {10,-1,-1},{11,-1,-1},{12,-1,-1},{13,-1,-1},
 {14,15,-1},{16,-1,-1},{17,-1,-1},{18,19,-1},
 {20,-1,-1},{21,-1,-1},{22,23,-1},{24,-1,-1},
 {25,26,-1},{27,-1,-1},{28,-1,-1},{29,-1,-1},
 {30,-1,-1},{31,-1,-1},{32,33,-1},{34,-1,-1},
 {35,36,-1},{37,38,-1},{39,40,-1},{41,42,43}
};
// merge tables: blockIdx.y -> T = 2 + y; slice count + uids (slices ascend in c)
__device__ __constant__ signed char MT_S[14] = {2,2,2,3,2,2,3,3,4,4,3,4,4,4};
__device__ __constant__ signed char MT_U[14][4] = {
 {40,41,-1,-1},{38,39,-1,-1},{36,37,-1,-1},{33,34,35,-1},
 {31,32,-1,-1},{29,30,-1,-1},{26,27,28,-1},{23,24,25,-1},
 {19,20,21,22},{15,16,17,18},{12,13,14,-1},{ 8, 9,10,11},
 { 4, 5, 6, 7},{ 0, 1, 2, 3}
};

// prefix of causal chunk counts over 32-row bias tiles
__device__ __forceinline__ int ftri(int t) {
    const int m = t >> 1;
    return (t & 1) ? (m + 1) * (m + 1) : m * (m + 1);
}

__device__ __forceinline__ void gload_lds16(const __bf16* gsrc, __bf16* ldst) {
    // 16B per lane; LDS dest = wave-uniform base + lane*16 (HW rule).
    __builtin_amdgcn_global_load_lds(
        (const __attribute__((address_space(1))) unsigned int*)gsrc,
        (__attribute__((address_space(3))) unsigned int*)ldst, 16, 0, 0);
}

// Pl swizzle (R7-proven: SQ_LDS_BANK_CONFLICT = 0): col ^ ((row&7)<<3);
// 8-groups move whole so bf16x8 reads stay contiguous.
__device__ __forceinline__ int pswz(int row, int col) {
    return col ^ ((row & 7) << 3);
}

// ---- DPP 16-lane row reductions (VALU pipe, no LDS/lgkm) ----
template<int CTRL>
__device__ __forceinline__ float dpp_mv(float v) {
    return __builtin_bit_cast(float,
        __builtin_amdgcn_update_dpp(0, __builtin_bit_cast(int, v),
                                    CTRL, 0xF, 0xF, true));
}
__device__ __forceinline__ float rmax16(float v) {
    v = fmaxf(v, dpp_mv<0xB1>(v));
    v = fmaxf(v, dpp_mv<0x4E>(v));
    v = fmaxf(v, dpp_mv<0x141>(v));
    v = fmaxf(v, dpp_mv<0x140>(v));
    return v;
}
__device__ __forceinline__ float rsum16(float v) {
    v += dpp_mv<0xB1>(v);
    v += dpp_mv<0x4E>(v);
    v += dpp_mv<0x141>(v);
    v += dpp_mv<0x140>(v);
    return v;
}

// ---- fused prep (verbatim — correctness-proven) ----
__global__ __launch_bounds__(256) void prep_fused(
    const float* __restrict__ K, const float* __restrict__ V,
    const int* __restrict__ imask,
    const float* __restrict__ b0, const float* __restrict__ b1,
    const float* __restrict__ b2, const float* __restrict__ b3,
    __bf16* __restrict__ Kp, __bf16* __restrict__ Vp, float* __restrict__ bsp)
{
    __shared__ __align__(16) __bf16 Ks[64][136];
    __shared__ __align__(16) __bf16 Vs[64][136];
    __shared__ __align__(16) float  Ts[32][68];
    const int bid = blockIdx.x;
    const int tid = threadIdx.x;

    if (bid >= 512) {
        const int u = bid - 512;               // unit in [0,1056)
        int t = 0;
        while (ftri(t + 1) <= u) ++t;          // <=64 scalar iters, once per block
        const int c = u - ftri(t);

        #pragma unroll
        for (int i = 0; i < 2; ++i) {
            const int v = tid + 256 * i;
            const int row = v >> 4, c4 = v & 15;
            const size_t g = (size_t)(t * 32 + row) * Nc + c * 64 + c4 * 4;
            const float4 a = *(const float4*)(b0 + g);
            const float4 d = *(const float4*)(b1 + g);
            const float4 e = *(const float4*)(b2 + g);
            const float4 f = *(const float4*)(b3 + g);
            float4 s;
            s.x = a.x + d.x + e.x + f.x;
            s.y = a.y + d.y + e.y + f.y;
            s.z = a.z + d.z + e.z + f.z;
            s.w = a.w + d.w + e.w + f.w;
            *(float4*)&Ts[row][c4 * 4] = s;
        }
        __syncthreads();

        const int lane = tid >> 2;
        const int quad = lane >> 4, l15 = lane & 15;
        const int k0 = (tid & 3) * 8;
        float* outp = bsp + (size_t)u * 2048;
        #pragma unroll
        for (int g2 = 0; g2 < 2; ++g2) {
            const int k = k0 + g2 * 4;
            const int h = (k >> 4) & 1, jt = (k >> 2) & 3;
            float4 o;
            o.x = Ts[h * 16 + quad * 4 + 0][jt * 16 + l15];
            o.y = Ts[h * 16 + quad * 4 + 1][jt * 16 + l15];
            o.z = Ts[h * 16 + quad * 4 + 2][jt * 16 + l15];
            o.w = Ts[h * 16 + quad * 4 + 3][jt * 16 + l15];
            ((float4*)outp)[tid * 2 + g2] = o;
        }
        return;
    }

    const int c = bid & 31;
    const int b = bid >> 5;
    const int m0 = c * 64;
    const float* Kb = K + (size_t)b * Nc * Dc;
    const float* Vb = V + (size_t)b * Nc * Dc;
    const int* imb = imask + b * Nc;

    #pragma unroll
    for (int it = 0; it < 8; ++it) {
        const int idx = it * 256 + tid;
        const int row = idx >> 5;
        const int c4  = idx & 31;
        const int gm  = m0 + row;
        const float msk = imb[gm] ? 1.0f : 0.0f;
        const float4 kf = ((const float4*)(Kb + (size_t)gm * Dc))[c4];
        const float4 vf = ((const float4*)(Vb + (size_t)gm * Dc))[c4];
        bf16x4 kb, vb;
        kb[0] = (__bf16)(kf.x * msk); kb[1] = (__bf16)(kf.y * msk);
        kb[2] = (__bf16)(kf.z * msk); kb[3] = (__bf16)(kf.w * msk);
        vb[0] = (__bf16)(vf.x * msk); vb[1] = (__bf16)(vf.y * msk);
        vb[2] = (__bf16)(vf.z * msk); vb[3] = (__bf16)(vf.w * msk);
        *(bf16x4*)&Ks[row][c4 * 4] = kb;
        *(bf16x4*)&Vs[row][c4 * 4] = vb;
    }
    __syncthreads();

    const size_t chunk_base = (size_t)(b * NCHUNK + c) * CHUNK_ELEMS;
    #pragma unroll
    for (int i = 0; i < 4; ++i) {
        const int s = i * 256 + tid;
        const int f = s >> 6;
        const int l = s & 63;
        const int quad = (l >> 4) & 3;
        const int l15  = l & 15;
        {   // K frag f=jt*4+kd
            const int jt = f >> 2, kd = f & 3;
            const bf16x8 kv = *(const bf16x8*)&Ks[jt * 16 + l15][kd * 32 + quad * 8];
            *(bf16x8*)&Kp[chunk_base + (size_t)f * 512 + l * 8] = kv;
        }
        {   // V frag f=kj*8+dt
            const int kj = f >> 3, dt = f & 7;
            bf16x8 vv;
            #pragma unroll
            for (int j = 0; j < 8; ++j)
                vv[j] = Vs[kj * 32 + quad * 8 + j][dt * 16 + l15];
            *(bf16x8*)&Vp[chunk_base + (size_t)f * 512 + l * 8] = vv;
        }
    }
}

// ---- main: 8-wave persistent flash attention, 128-row tiles ----
// R7 post-mortem: V-in-reg blew VGPR to 132 (>128 cliff) -> 10% occupancy.
// This keeps R6's PROVEN per-wave body and K+V LDS double-buffer, but in
// 512-thread blocks on 128-row tiles: LDS = 32+32+16 KB = 81920 B -> exactly
// 2 blocks/CU = 16 waves/CU = 4 waves/SIMD (2x R6). launch_bounds(512,4)
// caps VGPR at 128 — safe: R6's body measured 104 live. lrun row-reduction
// deferred to the epilogue (-32 VALU/chunk, exact).
template<bool SPLIT>
__global__ __launch_bounds__(512, 4) void attn8(
    const float* __restrict__ Q,
    const __bf16* __restrict__ Kp, const __bf16* __restrict__ Vp,
    const float* __restrict__ biasp, const int* __restrict__ emask,
    float* __restrict__ out, float* __restrict__ part)
{
    __shared__ __align__(16) __bf16 Kl[2][16 * 512];   // 2 x 16KB
    __shared__ __align__(16) __bf16 Vl[2][16 * 512];   // 2 x 16KB
    __shared__ __align__(16) __bf16 Pl[8][16][64];     // swizzled, 16KB

    const int tid  = threadIdx.x;
    const int w    = tid >> 6;
    const int lane = tid & 63;
    const int quad = lane >> 4;
    const int l15  = lane & 15;
    const int b    = blockIdx.x;
    const int slot = blockIdx.y;

    const float*  Qb  = Q + (size_t)b * Nc * Dc;
    const __bf16* Kpb = Kp + (size_t)b * NCHUNK * CHUNK_ELEMS;
    const __bf16* Vpb = Vp + (size_t)b * NCHUNK * CHUNK_ELEMS;
    const f32x4* bfragbase = (const f32x4*)biasp + (size_t)lane * 8 + (w & 1) * 4;

    for (int j = 0; j < 3; ++j) {
        int T, c0, cend, uid;
        bool direct;
        if (SPLIT) {
            T = ST_T[slot][j];
            if (T < 0) break;
            c0 = ST_C0[slot][j]; cend = ST_C1[slot][j]; uid = ST_U[slot][j];
            direct = (uid >= 42);
        } else {
            if (j) break;
            T = slot; c0 = 0; cend = 2 * T + 2; direct = true; uid = 0;
        }

        const int q0w = T * 128 + w * 16;
        const int t32 = T * 4 + (w >> 1);      // 32-row bias-tile index
        const int fb32 = ftri(t32);
        const int cdiag = 2 * T;               // mask needed for c >= cdiag
        const f32x4* bfrag = bfragbase;

        // ---- Q fragments (emask + SCALE folded) ----
        bf16x8 qfrag[4];
        {
            const int row = q0w + l15;
            const float qs = emask[b * Nc + row] ? SCALE_F : 0.0f;
            const float4* qr = (const float4*)(Qb + (size_t)row * Dc);
            #pragma unroll
            for (int kd = 0; kd < 4; ++kd) {
                const float4 xx = qr[kd * 8 + quad * 2];
                const float4 yy = qr[kd * 8 + quad * 2 + 1];
                qfrag[kd][0] = (__bf16)(xx.x * qs); qfrag[kd][1] = (__bf16)(xx.y * qs);
                qfrag[kd][2] = (__bf16)(xx.z * qs); qfrag[kd][3] = (__bf16)(xx.w * qs);
                qfrag[kd][4] = (__bf16)(yy.x * qs); qfrag[kd][5] = (__bf16)(yy.y * qs);
                qfrag[kd][6] = (__bf16)(yy.z * qs); qfrag[kd][7] = (__bf16)(yy.w * qs);
            }
        }

        f32x4 oacc[8];
        #pragma unroll
        for (int dt = 0; dt < 8; ++dt) { oacc[dt][0]=0.f; oacc[dt][1]=0.f; oacc[dt][2]=0.f; oacc[dt][3]=0.f; }
        float mrun[4] = {-INFINITY, -INFINITY, -INFINITY, -INFINITY};
        float lrun[4] = {0.f, 0.f, 0.f, 0.f};   // per-lane partial; row-reduced at epilogue

        const int nch = cend - c0;

        // ---- prologue: DMA chunk c0 -> buf0 (8 waves x 2 segs each) ----
        #pragma unroll
        for (int i = 0; i < 2; ++i) {
            const int seg = w * 2 + i;
            gload_lds16(Kpb + (size_t)c0 * CHUNK_ELEMS + seg * 512 + lane * 8, &Kl[0][seg * 512]);
            gload_lds16(Vpb + (size_t)c0 * CHUNK_ELEMS + seg * 512 + lane * 8, &Vl[0][seg * 512]);
        }
        f32x4 binit[4];
        #pragma unroll
        for (int jt = 0; jt < 4; ++jt)
            binit[jt] = bfrag[(size_t)(fb32 + c0) * 512 + jt];
        __syncthreads();   // drain: chunk-c0 DMA landed

        // ---- QK(c0) with bias as C-init ----
        f32x4 sc[4];
        #pragma unroll
        for (int jt = 0; jt < 4; ++jt) sc[jt] = binit[jt];
        #pragma unroll
        for (int jt = 0; jt < 4; ++jt)
            #pragma unroll
            for (int kd = 0; kd < 4; ++kd) {
                const bf16x8 bfr = *(const bf16x8*)&Kl[0][(jt * 4 + kd) * 512 + lane * 8];
                sc[jt] = __builtin_amdgcn_mfma_f32_16x16x32_bf16(qfrag[kd], bfr, sc[jt], 0, 0, 0);
            }
        if (nch > 1) {
            #pragma unroll
            for (int i = 0; i < 2; ++i) {
                const int seg = w * 2 + i;
                gload_lds16(Kpb + (size_t)(c0 + 1) * CHUNK_ELEMS + seg * 512 + lane * 8, &Kl[1][seg * 512]);
                gload_lds16(Vpb + (size_t)(c0 + 1) * CHUNK_ELEMS + seg * 512 + lane * 8, &Vl[1][seg * 512]);
            }
            #pragma unroll
            for (int jt = 0; jt < 4; ++jt)
                binit[jt] = bfrag[(size_t)(fb32 + c0 + 1) * 512 + jt];
        }

        for (int c = c0; c < cend; ++c) {
            const int cb = (c - c0) & 1;

            // ---- causal mask (diag chunk is 2T for waves 0-3, 2T+1 for 4-7;
            //      chunk 2T+1 is all-masked for waves 0-3 — mrun already finite
            //      because every slice containing 2T+1 also contains <=2T) ----
            if (c >= cdiag) {
                const int m0 = c * 64;
                #pragma unroll
                for (int jt = 0; jt < 4; ++jt)
                    #pragma unroll
                    for (int reg = 0; reg < 4; ++reg) {
                        const int gr = q0w + quad * 4 + reg;
                        const int gc = m0 + jt * 16 + l15;
                        if (gc > gr) sc[jt][reg] = -INFINITY;
                    }
            }

            // ---- online softmax; exact rescale-skip when no row max grows ----
            float mx[4];
            int grow = 0;
            #pragma unroll
            for (int reg = 0; reg < 4; ++reg) {
                float m = fmaxf(fmaxf(sc[0][reg], sc[1][reg]), fmaxf(sc[2][reg], sc[3][reg]));
                m = rmax16(m);
                mx[reg] = m;
                grow |= (m > mrun[reg]);
            }
            if (__any(grow)) {   // wave-uniform; skip path is numerically exact
                #pragma unroll
                for (int reg = 0; reg < 4; ++reg) {
                    const float mn = fmaxf(mrun[reg], mx[reg]);
                    const float alpha = __expf(mrun[reg] - mn);  // first chunk: exp(-inf)=0
                    mrun[reg] = mn;
                    lrun[reg] *= alpha;
                    #pragma unroll
                    for (int dt = 0; dt < 8; ++dt) oacc[dt][reg] *= alpha;
                }
            }
            #pragma unroll
            for (int reg = 0; reg < 4; ++reg) {
                float ls = 0.f;
                #pragma unroll
                for (int jt = 0; jt < 4; ++jt) {
                    const float pv = __expf(sc[jt][reg] - mrun[reg]);  // masked: exp(-inf)=0
                    sc[jt][reg] = pv;
                    ls += pv;
                }
                lrun[reg] += ls;   // per-lane partial; rsum16 deferred to epilogue
            }

            // ---- P: C-layout -> LDS (swizzled) -> A-layout ----
            #pragma unroll
            for (int jt = 0; jt < 4; ++jt)
                #pragma unroll
                for (int reg = 0; reg < 4; ++reg) {
                    const int row = quad * 4 + reg;
                    Pl[w][row][pswz(row, jt * 16 + l15)] = (__bf16)sc[jt][reg];
                }
            // same-wave write->read; compiler inserts lgkmcnt wait

            // ---- O += P V ----
            #pragma unroll
            for (int kj = 0; kj < 2; ++kj) {
                const bf16x8 pa = *(const bf16x8*)&Pl[w][l15][pswz(l15, kj * 32 + quad * 8)];
                #pragma unroll
                for (int dt = 0; dt < 8; ++dt) {
                    const bf16x8 vb = *(const bf16x8*)&Vl[cb][(kj * 8 + dt) * 512 + lane * 8];
                    oacc[dt] = __builtin_amdgcn_mfma_f32_16x16x32_bf16(pa, vb, oacc[dt], 0, 0, 0);
                }
            }

            // single barrier: all waves done reading Kl[cb]/Vl[cb]; vmcnt drain
            // covers DMA(c+1) (issued a full iteration ago -> near-free).
            __syncthreads();

            const bool n1 = (c + 1) < cend;
            const bool n2 = (c + 2) < cend;

            // ---- DMA chunk c+2 into buf[cb] (K(c)/V(c) both retired) ----
            if (n2) {
                const size_t off = (size_t)(c + 2) * CHUNK_ELEMS;
                #pragma unroll
                for (int i = 0; i < 2; ++i) {
                    const int seg = w * 2 + i;
                    gload_lds16(Kpb + off + seg * 512 + lane * 8, &Kl[cb][seg * 512]);
                    gload_lds16(Vpb + off + seg * 512 + lane * 8, &Vl[cb][seg * 512]);
                }
            }

            // ---- QK(c+1) from Kl[cb^1]; prefetched bias as C-init ----
            if (n1) {
                #pragma unroll
                for (int jt = 0; jt < 4; ++jt) sc[jt] = binit[jt];
                #pragma unroll
                for (int jt = 0; jt < 4; ++jt)
                    #pragma unroll
                    for (int kd = 0; kd < 4; ++kd) {
                        const bf16x8 bfr = *(const bf16x8*)&Kl[cb ^ 1][(jt * 4 + kd) * 512 + lane * 8];
                        sc[jt] = __builtin_amdgcn_mfma_f32_16x16x32_bf16(qfrag[kd], bfr, sc[jt], 0, 0, 0);
                    }
            }
            if (n2) {
                #pragma unroll
                for (int jt = 0; jt < 4; ++jt)
                    binit[jt] = bfrag[(size_t)(fb32 + c + 2) * 512 + jt];
            }
        }

        // ---- epilogue (deferred lrun row-reduction) ----
        if (direct) {
            #pragma unroll
            for (int reg = 0; reg < 4; ++reg) {
                const float inv = 1.0f / rsum16(lrun[reg]);
                const int gr = q0w + quad * 4 + reg;
                float* orow = out + ((size_t)b * Nc + gr) * Dc;
                #pragma unroll
                for (int dt = 0; dt < 8; ++dt)
                    orow[dt * 16 + l15] = oacc[dt][reg] * inv;
            }
        } else {
            float* pb = part + (size_t)(b * NPART8 + uid) * PART_FLOATS8;
            #pragma unroll
            for (int reg = 0; reg < 4; ++reg) {
                const int lr = w * 16 + quad * 4 + reg;
                #pragma unroll
                for (int dt = 0; dt < 8; ++dt)
                    pb[lr * 128 + dt * 16 + l15] = oacc[dt][reg];
                const float ls = rsum16(lrun[reg]);
                if (l15 == 0) {
                    pb[16384 + lr] = mrun[reg];
                    pb[16512 + lr] = ls;
                }
            }
        }
        // next unit's prologue DMA is safe: all Kl/Vl reads completed before
        // the final barrier of this unit's loop (epilogue is reg/global only).
    }
}

// ---- merge <=4 split partials per (b, 128-row tile T=2..15) ----
__global__ __launch_bounds__(256) void merge_parts8(
    const float* __restrict__ part, float* __restrict__ out)
{
    const int b = blockIdx.x;
    const int y = blockIdx.y;              // T = 2 + y
    const int T = 2 + y;
    const int S = MT_S[y];
    const int r  = threadIdx.x >> 1;       // row 0..127
    const int ch = threadIdx.x & 1;        // col half (64 cols)

    const float* pb[4];
    float m[4], a[4];
    float mstar = -INFINITY;
    #pragma unroll
    for (int s = 0; s < 4; ++s)
        if (s < S) {
            pb[s] = part + (size_t)(b * NPART8 + MT_U[y][s]) * PART_FLOATS8;
            m[s] = pb[s][16384 + r];
            mstar = fmaxf(mstar, m[s]);
        }
    float lsum = 0.f;
    #pragma unroll
    for (int s = 0; s < 4; ++s)
        if (s < S) {
            a[s] = __expf(m[s] - mstar);
            lsum += pb[s][16512 + r] * a[s];
        }
    const float inv = 1.0f / lsum;

    float* orow = out + ((size_t)b * Nc + T * 128 + r) * Dc + ch * 64;
    #pragma unroll
    for (int i = 0; i < 16; ++i) {
        float x = 0.f, yv = 0.f, z = 0.f, ww = 0.f;
        #pragma unroll
        for (int s = 0; s < 4; ++s)
            if (s < S) {
                const f32x4 v = *(const f32x4*)&pb[s][r * 128 + ch * 64 + i * 4];
                x += v[0] * a[s]; yv += v[1] * a[s]; z += v[2] * a[s]; ww += v[3] * a[s];
            }
        f32x4 o; o[0] = x * inv; o[1] = yv * inv; o[2] = z * inv; o[3] = ww * inv;
        *(f32x4*)&orow[i * 4] = o;
    }
}

// ---- legacy fallback (in-kernel staging, 4 bias reads) for tiny ws ----
__global__ __launch_bounds__(256) void attn_mfma_legacy(
    const float* __restrict__ Q, const float* __restrict__ K, const float* __restrict__ V,
    const float* __restrict__ p0, const float* __restrict__ p1,
    const float* __restrict__ p2, const float* __restrict__ p3,
    const int* __restrict__ imask, const int* __restrict__ emask,
    float* __restrict__ out)
{
    __shared__ __align__(16) __bf16 Klds[64][136];
    __shared__ __align__(16) __bf16 Vt[128][72];
    __shared__ __align__(16) __bf16 Plds[4][16][72];
    const int tid  = threadIdx.x;
    const int w    = tid >> 6;
    const int lane = tid & 63;
    const int quad = lane >> 4;
    const int l15  = lane & 15;
    const int b = blockIdx.y;
    const int x = blockIdx.x, yy = blockIdx.y;
    const int ti = (yy < 8) ? x : (31 - x);
    const int q0 = ti * 64, q0w = q0 + w * 16;
    const float* Qb = Q + (size_t)b * Nc * Dc;
    const float* Kb = K + (size_t)b * Nc * Dc;
    const float* Vb = V + (size_t)b * Nc * Dc;
    const int* imb = imask + b * Nc;

    bf16x8 qfrag[4];
    {
        const int row = q0w + l15;
        const float qs = emask[b * Nc + row] ? SCALE_F : 0.0f;
        const float4* qr = (const float4*)(Qb + (size_t)row * Dc);
        #pragma unroll
        for (int kd = 0; kd < 4; ++kd) {
            const float4 xv = qr[kd * 8 + quad * 2];
            const float4 yv = qr[kd * 8 + quad * 2 + 1];
            qfrag[kd][0]=(__bf16)(xv.x*qs); qfrag[kd][1]=(__bf16)(xv.y*qs);
            qfrag[kd][2]=(__bf16)(xv.z*qs); qfrag[kd][3]=(__bf16)(xv.w*qs);
            qfrag[kd][4]=(__bf16)(yv.x*qs); qfrag[kd][5]=(__bf16)(yv.y*qs);
            qfrag[kd][6]=(__bf16)(yv.z*qs); qfrag[kd][7]=(__bf16)(yv.w*qs);
        }
    }
    f32x4 oacc[8];
    #pragma unroll
    for (int dt = 0; dt < 8; ++dt){oacc[dt][0]=0.f;oacc[dt][1]=0.f;oacc[dt][2]=0.f;oacc[dt][3]=0.f;}
    float mrun[4]={-INFINITY,-INFINITY,-INFINITY,-INFINITY}, lrun[4]={0.f,0.f,0.f,0.f};

    for (int m0 = 0; m0 <= q0; m0 += 64) {
        __syncthreads();
        #pragma unroll
        for (int it = 0; it < 8; ++it) {
            const int idx = it * 256 + tid;
            const int row = idx >> 5, c4 = idx & 31;
            const int gm = m0 + row;
            const float msk = imb[gm] ? 1.0f : 0.0f;
            const float4 kf = ((const float4*)(Kb + (size_t)gm * Dc))[c4];
            const float4 vf = ((const float4*)(Vb + (size_t)gm * Dc))[c4];
            bf16x4 kb;
            kb[0]=(__bf16)(kf.x*msk); kb[1]=(__bf16)(kf.y*msk);
            kb[2]=(__bf16)(kf.z*msk); kb[3]=(__bf16)(kf.w*msk);
            *(bf16x4*)&Klds[row][c4*4] = kb;
            Vt[c4*4+0][row]=(__bf16)(vf.x*msk); Vt[c4*4+1][row]=(__bf16)(vf.y*msk);
            Vt[c4*4+2][row]=(__bf16)(vf.z*msk); Vt[c4*4+3][row]=(__bf16)(vf.w*msk);
        }
        __syncthreads();
        f32x4 sc[4];
        #pragma unroll
        for (int jt = 0; jt < 4; ++jt){sc[jt][0]=0.f;sc[jt][1]=0.f;sc[jt][2]=0.f;sc[jt][3]=0.f;}
        #pragma unroll
        for (int jt = 0; jt < 4; ++jt)
            #pragma unroll
            for (int kd = 0; kd < 4; ++kd) {
                const bf16x8 bfr = *(const bf16x8*)&Klds[jt*16+l15][kd*32+quad*8];
                sc[jt] = __builtin_amdgcn_mfma_f32_16x16x32_bf16(qfrag[kd], bfr, sc[jt], 0, 0, 0);
            }
        #pragma unroll
        for (int jt = 0; jt < 4; ++jt)
            #pragma unroll
            for (int reg = 0; reg < 4; ++reg) {
                const int gr = q0w + quad*4 + reg;
                const int gc = m0 + jt*16 + l15;
                const size_t boff = (size_t)gr * Nc + gc;
                const float bsx = p0[boff] + p1[boff] + p2[boff] + p3[boff];
                const float v = sc[jt][reg] + bsx;
                sc[jt][reg] = (gc > gr) ? -INFINITY : v;
            }
        #pragma unroll
        for (int reg = 0; reg < 4; ++reg) {
            float mx = fmaxf(fmaxf(sc[0][reg], sc[1][reg]), fmaxf(sc[2][reg], sc[3][reg]));
            mx = rmax16(mx);
            const float mn = fmaxf(mrun[reg], mx);
            const float alpha = __expf(mrun[reg] - mn);
            mrun[reg] = mn; lrun[reg] *= alpha;
            #pragma unroll
            for (int dt = 0; dt < 8; ++dt) oacc[dt][reg] *= alpha;
            float ls = 0.f;
            #pragma unroll
            for (int jt = 0; jt < 4; ++jt) {
                const float pv = __expf(sc[jt][reg] - mn);
                sc[jt][reg] = pv; ls += pv;
            }
            lrun[reg] += rsum16(ls);
        }
        #pragma unroll
        for (int jt = 0; jt < 4; ++jt)
            #pragma unroll
            for (int reg = 0; reg < 4; ++reg)
                Plds[w][quad*4+reg][jt*16+l15] = (__bf16)sc[jt][reg];
        #pragma unroll
        for (int kj = 0; kj < 2; ++kj) {
            const bf16x8 pa = *(const bf16x8*)&Plds[w][l15][kj*32+quad*8];
            #pragma unroll
            for (int dt = 0; dt < 8; ++dt) {
                const bf16x8 vb = *(const bf16x8*)&Vt[dt*16+l15][kj*32+quad*8];
                oacc[dt] = __builtin_amdgcn_mfma_f32_16x16x32_bf16(pa, vb, oacc[dt], 0, 0, 0);
            }
        }
    }
    #pragma unroll
    for (int reg = 0; reg < 4; ++reg) {
        const float inv = 1.0f / lrun[reg];
        const int gr = q0w + quad*4 + reg;
        float* orow = out + ((size_t)b * Nc + gr) * Dc;
        #pragma unroll
        for (int dt = 0; dt < 8; ++dt)
            orow[dt*16+l15] = oacc[dt][reg] * inv;
    }
}

extern "C" void kernel_launch(void* const* d_in, const int* in_sizes, int n_in,
                              void* d_out, int out_size, void* d_ws, size_t ws_size,
                              hipStream_t stream) {
    const float* Q  = (const float*)d_in[0];
    const float* K  = (const float*)d_in[1];
    const float* V  = (const float*)d_in[2];
    const float* b0 = (const float*)d_in[3];
    const float* b1 = (const float*)d_in[4];
    const float* b2 = (const float*)d_in[5];
    const float* b3 = (const float*)d_in[6];
    const int* im   = (const int*)d_in[7];
    const int* em   = (const int*)d_in[8];
    float* out      = (float*)d_out;

    const size_t need_full  = KPACK_BYTES + VPACK_BYTES + BIASP_BYTES;
    const size_t need_split = need_full + PART_BYTES8;

    if (ws_size >= need_full) {
        __bf16* Kp  = (__bf16*)d_ws;
        __bf16* Vp  = (__bf16*)((char*)d_ws + KPACK_BYTES);
        float*  bsp = (float*)((char*)d_ws + KPACK_BYTES + VPACK_BYTES);
        float*  prt = (float*)((char*)d_ws + need_full);
        prep_fused<<<512 + NUNITS, 256, 0, stream>>>(
            K, V, im, b0, b1, b2, b3, Kp, Vp, bsp);
        if (ws_size >= need_split) {
            attn8<true><<<dim3(Bc, 32), 512, 0, stream>>>(
                Q, Kp, Vp, bsp, em, out, prt);
            merge_parts8<<<dim3(Bc, 14), 256, 0, stream>>>(prt, out);
        } else {
            attn8<false><<<dim3(Bc, 16), 512, 0, stream>>>(
                Q, Kp, Vp, bsp, em, out, nullptr);
        }
    } else {
        attn_mfma_legacy<<<dim3(NCHUNK, Bc), 256, 0, stream>>>(
            Q, K, V, b0, b1, b2, b3, im, em, out);
    }
}

// Round 9
// 252.234 us; speedup vs baseline: 1.1293x; 1.1293x over previous
//
#include <hip/hip_runtime.h>
#include <math.h>

// (B, N, D) = (16, 2048, 128)
constexpr int Bc = 16;
constexpr int Nc = 2048;
constexpr int Dc = 128;
constexpr int NCHUNK = Nc / 64;          // 32 key-chunks of 64
constexpr float SCALE_F = 0.08838834764831845f;  // 1/sqrt(128)

typedef __bf16 bf16x8 __attribute__((ext_vector_type(8)));
typedef __bf16 bf16x4 __attribute__((ext_vector_type(4)));
typedef float  f32x4  __attribute__((ext_vector_type(4)));

// ws layout: Kpack 8MB | Vpack 8MB | bias_packed 8.65MB | partials 44.7MB
constexpr size_t KPACK_BYTES = (size_t)Bc * NCHUNK * 16 * 64 * 16;
constexpr size_t VPACK_BYTES = KPACK_BYTES;
constexpr int NUNITS = 1056;             // bias units: sum_t C(t), t32 in [0,64)
constexpr size_t BIASP_BYTES = (size_t)NUNITS * 2048 * 4;
constexpr int CHUNK_ELEMS = 16 * 64 * 8; // 8192 bf16 = 16KB per chunk
// 128-row-tile partials: 42 partial units per b, each 128x128 O + m[128] + l[128]
constexpr int PART_FLOATS8 = 128 * 128 + 128 + 128;   // 16640
constexpr int NPART8 = 42;
constexpr size_t PART_BYTES8 = (size_t)Bc * NPART8 * PART_FLOATS8 * 4;

// ---- 8-wave persistent schedule (R8, harness-verified) ----
// Per b: 16 tiles of 128 rows; tile T has 2T+2 chunks (272 total), sliced into
// 44 contiguous units packed into 32 slots: slots 0-15 run 9 chunks, 16-31 run
// 8. Co-resident CU pair (s, s+16) sums to exactly 17 chunks. Units 42,43
// (tiles T1, T0) are single-slice -> direct write; units 0-41 write partials.
__device__ __constant__ signed char ST_T[32][3] = {
 {15,-1,-1},{15,-1,-1},{15,-1,-1},{15,14,-1},
 {14,-1,-1},{14,-1,-1},{14,13,-1},{13,-1,-1},
 {13,-1,-1},{13,-1,-1},{12,-1,-1},{12,-1,-1},
 {12,11,-1},{11,-1,-1},{11,-1,-1},{11,10,-1},
 {10,-1,-1},{10,-1,-1},{10, 9,-1},{ 9,-1,-1},
 { 9, 8,-1},{ 8,-1,-1},{ 8,-1,-1},{ 7,-1,-1},
 { 7,-1,-1},{ 6,-1,-1},{ 6, 5,-1},{ 5,-1,-1},
 { 5, 4,-1},{ 4, 3,-1},{ 3, 2,-1},{ 2, 1, 0}
};
__device__ __constant__ signed char ST_C0[32][3] = {
 { 0, 0, 0},{ 9, 0, 0},{18, 0, 0},{27, 0, 0},
 { 4, 0, 0},{13, 0, 0},{22, 0, 0},{ 1, 0, 0},
 {10, 0, 0},{19, 0, 0},{ 0, 0, 0},{ 9, 0, 0},
 {18, 0, 0},{ 1, 0, 0},{10, 0, 0},{19, 0, 0},
 { 4, 0, 0},{12, 0, 0},{20, 0, 0},{ 6, 0, 0},
 {14, 0, 0},{ 2, 0, 0},{10, 0, 0},{ 0, 0, 0},
 { 8, 0, 0},{ 0, 0, 0},{ 8, 0, 0},{ 2, 0, 0},
 {10, 0, 0},{ 6, 0, 0},{ 4, 0, 0},{ 4, 0, 0}
};
__device__ __constant__ signed char ST_C1[32][3] = {
 { 9, 0, 0},{18, 0, 0},{27, 0, 0},{32, 4, 0},
 {13, 0, 0},{22, 0, 0},{30, 1, 0},{10, 0, 0},
 {19, 0, 0},{28, 0, 0},{ 9, 0, 0},{18, 0, 0},
 {26, 1, 0},{10, 0, 0},{19, 0, 0},{24, 4, 0},
 {12, 0, 0},{20, 0, 0},{22, 6, 0},{14, 0, 0},
 {20, 2, 0},{10, 0, 0},{18, 0, 0},{ 8, 0, 0},
 {16, 0, 0},{ 8, 0, 0},{14, 2, 0},{10, 0, 0},
 {12, 6, 0},{10, 4, 0},{ 8, 4, 0},{ 6, 4, 2}
};
__device__ __constant__ signed char ST_U[32][3] = {
 { 0,-1,-1},{ 1,-1,-1},{ 2,-1,-1},{ 3, 4,-1},
 { 5,-1,-1},{ 6,-1,-1},{ 7, 8,-1},{ 9,-1,-1},
 {10,-1,-1},{11,-1,-1},{12,-1,-1},{13,-1,-1},
 {14,15,-1},{16,-1,-1},{17,-1,-1},{18,19,-1},
 {20,-1,-1},{21,-1,-1},{22,23,-1},{24,-1,-1},
 {25,26,-1},{27,-1,-1},{28,-1,-1},{29,-1,-1},
 {30,-1,-1},{31,-1,-1},{32,33,-1},{34,-1,-1},
 {35,36,-1},{37,38,-1},{39,40,-1},{41,42,43}
};
// merge tables: blockIdx.y -> T = 2 + y; slice count + uids (slices ascend in c)
__device__ __constant__ signed char MT_S[14] = {2,2,2,3,2,2,3,3,4,4,3,4,4,4};
__device__ __constant__ signed char MT_U[14][4] = {
 {40,41,-1,-1},{38,39,-1,-1},{36,37,-1,-1},{33,34,35,-1},
 {31,32,-1,-1},{29,30,-1,-1},{26,27,28,-1},{23,24,25,-1},
 {19,20,21,22},{15,16,17,18},{12,13,14,-1},{ 8, 9,10,11},
 { 4, 5, 6, 7},{ 0, 1, 2, 3}
};

// prefix of causal chunk counts over 32-row bias tiles
__device__ __forceinline__ int ftri(int t) {
    const int m = t >> 1;
    return (t & 1) ? (m + 1) * (m + 1) : m * (m + 1);
}

__device__ __forceinline__ void gload_lds16(const __bf16* gsrc, __bf16* ldst) {
    // 16B per lane; LDS dest = wave-uniform base + lane*16 (HW rule).
    __builtin_amdgcn_global_load_lds(
        (const __attribute__((address_space(1))) unsigned int*)gsrc,
        (__attribute__((address_space(3))) unsigned int*)ldst, 16, 0, 0);
}

// Pl swizzle (R7-proven: SQ_LDS_BANK_CONFLICT = 0): col ^ ((row&7)<<3);
// 8-groups move whole so bf16x8 reads stay contiguous.
__device__ __forceinline__ int pswz(int row, int col) {
    return col ^ ((row & 7) << 3);
}

// ---- DPP 16-lane row reductions (VALU pipe, no LDS/lgkm) ----
template<int CTRL>
__device__ __forceinline__ float dpp_mv(float v) {
    return __builtin_bit_cast(float,
        __builtin_amdgcn_update_dpp(0, __builtin_bit_cast(int, v),
                                    CTRL, 0xF, 0xF, true));
}
__device__ __forceinline__ float rmax16(float v) {
    v = fmaxf(v, dpp_mv<0xB1>(v));
    v = fmaxf(v, dpp_mv<0x4E>(v));
    v = fmaxf(v, dpp_mv<0x141>(v));
    v = fmaxf(v, dpp_mv<0x140>(v));
    return v;
}
__device__ __forceinline__ float rsum16(float v) {
    v += dpp_mv<0xB1>(v);
    v += dpp_mv<0x4E>(v);
    v += dpp_mv<0x141>(v);
    v += dpp_mv<0x140>(v);
    return v;
}

// ---- fused prep (verbatim — correctness-proven) ----
__global__ __launch_bounds__(256) void prep_fused(
    const float* __restrict__ K, const float* __restrict__ V,
    const int* __restrict__ imask,
    const float* __restrict__ b0, const float* __restrict__ b1,
    const float* __restrict__ b2, const float* __restrict__ b3,
    __bf16* __restrict__ Kp, __bf16* __restrict__ Vp, float* __restrict__ bsp)
{
    __shared__ __align__(16) __bf16 Ks[64][136];
    __shared__ __align__(16) __bf16 Vs[64][136];
    __shared__ __align__(16) float  Ts[32][68];
    const int bid = blockIdx.x;
    const int tid = threadIdx.x;

    if (bid >= 512) {
        const int u = bid - 512;               // unit in [0,1056)
        int t = 0;
        while (ftri(t + 1) <= u) ++t;          // <=64 scalar iters, once per block
        const int c = u - ftri(t);

        #pragma unroll
        for (int i = 0; i < 2; ++i) {
            const int v = tid + 256 * i;
            const int row = v >> 4, c4 = v & 15;
            const size_t g = (size_t)(t * 32 + row) * Nc + c * 64 + c4 * 4;
            const float4 a = *(const float4*)(b0 + g);
            const float4 d = *(const float4*)(b1 + g);
            const float4 e = *(const float4*)(b2 + g);
            const float4 f = *(const float4*)(b3 + g);
            float4 s;
            s.x = a.x + d.x + e.x + f.x;
            s.y = a.y + d.y + e.y + f.y;
            s.z = a.z + d.z + e.z + f.z;
            s.w = a.w + d.w + e.w + f.w;
            *(float4*)&Ts[row][c4 * 4] = s;
        }
        __syncthreads();

        const int lane = tid >> 2;
        const int quad = lane >> 4, l15 = lane & 15;
        const int k0 = (tid & 3) * 8;
        float* outp = bsp + (size_t)u * 2048;
        #pragma unroll
        for (int g2 = 0; g2 < 2; ++g2) {
            const int k = k0 + g2 * 4;
            const int h = (k >> 4) & 1, jt = (k >> 2) & 3;
            float4 o;
            o.x = Ts[h * 16 + quad * 4 + 0][jt * 16 + l15];
            o.y = Ts[h * 16 + quad * 4 + 1][jt * 16 + l15];
            o.z = Ts[h * 16 + quad * 4 + 2][jt * 16 + l15];
            o.w = Ts[h * 16 + quad * 4 + 3][jt * 16 + l15];
            ((float4*)outp)[tid * 2 + g2] = o;
        }
        return;
    }

    const int c = bid & 31;
    const int b = bid >> 5;
    const int m0 = c * 64;
    const float* Kb = K + (size_t)b * Nc * Dc;
    const float* Vb = V + (size_t)b * Nc * Dc;
    const int* imb = imask + b * Nc;

    #pragma unroll
    for (int it = 0; it < 8; ++it) {
        const int idx = it * 256 + tid;
        const int row = idx >> 5;
        const int c4  = idx & 31;
        const int gm  = m0 + row;
        const float msk = imb[gm] ? 1.0f : 0.0f;
        const float4 kf = ((const float4*)(Kb + (size_t)gm * Dc))[c4];
        const float4 vf = ((const float4*)(Vb + (size_t)gm * Dc))[c4];
        bf16x4 kb, vb;
        kb[0] = (__bf16)(kf.x * msk); kb[1] = (__bf16)(kf.y * msk);
        kb[2] = (__bf16)(kf.z * msk); kb[3] = (__bf16)(kf.w * msk);
        vb[0] = (__bf16)(vf.x * msk); vb[1] = (__bf16)(vf.y * msk);
        vb[2] = (__bf16)(vf.z * msk); vb[3] = (__bf16)(vf.w * msk);
        *(bf16x4*)&Ks[row][c4 * 4] = kb;
        *(bf16x4*)&Vs[row][c4 * 4] = vb;
    }
    __syncthreads();

    const size_t chunk_base = (size_t)(b * NCHUNK + c) * CHUNK_ELEMS;
    #pragma unroll
    for (int i = 0; i < 4; ++i) {
        const int s = i * 256 + tid;
        const int f = s >> 6;
        const int l = s & 63;
        const int quad = (l >> 4) & 3;
        const int l15  = l & 15;
        {   // K frag f=jt*4+kd
            const int jt = f >> 2, kd = f & 3;
            const bf16x8 kv = *(const bf16x8*)&Ks[jt * 16 + l15][kd * 32 + quad * 8];
            *(bf16x8*)&Kp[chunk_base + (size_t)f * 512 + l * 8] = kv;
        }
        {   // V frag f=kj*8+dt
            const int kj = f >> 3, dt = f & 7;
            bf16x8 vv;
            #pragma unroll
            for (int j = 0; j < 8; ++j)
                vv[j] = Vs[kj * 32 + quad * 8 + j][dt * 16 + l15];
            *(bf16x8*)&Vp[chunk_base + (size_t)f * 512 + l * 8] = vv;
        }
    }
}

// ---- main: 8-wave persistent flash attention, 128-row tiles ----
// R8 post-mortem: structure CORRECT (passed) and occupancy goal hit (36%),
// but __launch_bounds__(512,4) made the allocator target 64 VGPR -> massive
// scratch spill (WRITE 93.6MB, +33MB pure spill). This round: identical code,
// hint REMOVED — natural allocation for this body measured 104 VGPR (R6),
// <=128 -> 4 waves/SIMD falls out naturally with LDS 81920 B (2 blocks/CU).
template<bool SPLIT>
__global__ __launch_bounds__(512) void attn8(
    const float* __restrict__ Q,
    const __bf16* __restrict__ Kp, const __bf16* __restrict__ Vp,
    const float* __restrict__ biasp, const int* __restrict__ emask,
    float* __restrict__ out, float* __restrict__ part)
{
    __shared__ __align__(16) __bf16 Kl[2][16 * 512];   // 2 x 16KB
    __shared__ __align__(16) __bf16 Vl[2][16 * 512];   // 2 x 16KB
    __shared__ __align__(16) __bf16 Pl[8][16][64];     // swizzled, 16KB

    const int tid  = threadIdx.x;
    const int w    = tid >> 6;
    const int lane = tid & 63;
    const int quad = lane >> 4;
    const int l15  = lane & 15;
    const int b    = blockIdx.x;
    const int slot = blockIdx.y;

    const float*  Qb  = Q + (size_t)b * Nc * Dc;
    const __bf16* Kpb = Kp + (size_t)b * NCHUNK * CHUNK_ELEMS;
    const __bf16* Vpb = Vp + (size_t)b * NCHUNK * CHUNK_ELEMS;
    const f32x4* bfragbase = (const f32x4*)biasp + (size_t)lane * 8 + (w & 1) * 4;

    for (int j = 0; j < 3; ++j) {
        int T, c0, cend, uid;
        bool direct;
        if (SPLIT) {
            T = ST_T[slot][j];
            if (T < 0) break;
            c0 = ST_C0[slot][j]; cend = ST_C1[slot][j]; uid = ST_U[slot][j];
            direct = (uid >= 42);
        } else {
            if (j) break;
            T = slot; c0 = 0; cend = 2 * T + 2; direct = true; uid = 0;
        }

        const int q0w = T * 128 + w * 16;
        const int t32 = T * 4 + (w >> 1);      // 32-row bias-tile index
        const int fb32 = ftri(t32);
        const int cdiag = 2 * T;               // mask needed for c >= cdiag
        const f32x4* bfrag = bfragbase;

        // ---- Q fragments (emask + SCALE folded) ----
        bf16x8 qfrag[4];
        {
            const int row = q0w + l15;
            const float qs = emask[b * Nc + row] ? SCALE_F : 0.0f;
            const float4* qr = (const float4*)(Qb + (size_t)row * Dc);
            #pragma unroll
            for (int kd = 0; kd < 4; ++kd) {
                const float4 xx = qr[kd * 8 + quad * 2];
                const float4 yy = qr[kd * 8 + quad * 2 + 1];
                qfrag[kd][0] = (__bf16)(xx.x * qs); qfrag[kd][1] = (__bf16)(xx.y * qs);
                qfrag[kd][2] = (__bf16)(xx.z * qs); qfrag[kd][3] = (__bf16)(xx.w * qs);
                qfrag[kd][4] = (__bf16)(yy.x * qs); qfrag[kd][5] = (__bf16)(yy.y * qs);
                qfrag[kd][6] = (__bf16)(yy.z * qs); qfrag[kd][7] = (__bf16)(yy.w * qs);
            }
        }

        f32x4 oacc[8];
        #pragma unroll
        for (int dt = 0; dt < 8; ++dt) { oacc[dt][0]=0.f; oacc[dt][1]=0.f; oacc[dt][2]=0.f; oacc[dt][3]=0.f; }
        float mrun[4] = {-INFINITY, -INFINITY, -INFINITY, -INFINITY};
        float lrun[4] = {0.f, 0.f, 0.f, 0.f};   // per-lane partial; row-reduced at epilogue

        const int nch = cend - c0;

        // ---- prologue: DMA chunk c0 -> buf0 (8 waves x 2 segs each) ----
        #pragma unroll
        for (int i = 0; i < 2; ++i) {
            const int seg = w * 2 + i;
            gload_lds16(Kpb + (size_t)c0 * CHUNK_ELEMS + seg * 512 + lane * 8, &Kl[0][seg * 512]);
            gload_lds16(Vpb + (size_t)c0 * CHUNK_ELEMS + seg * 512 + lane * 8, &Vl[0][seg * 512]);
        }
        f32x4 binit[4];
        #pragma unroll
        for (int jt = 0; jt < 4; ++jt)
            binit[jt] = bfrag[(size_t)(fb32 + c0) * 512 + jt];
        __syncthreads();   // drain: chunk-c0 DMA landed

        // ---- QK(c0) with bias as C-init ----
        f32x4 sc[4];
        #pragma unroll
        for (int jt = 0; jt < 4; ++jt) sc[jt] = binit[jt];
        #pragma unroll
        for (int jt = 0; jt < 4; ++jt)
            #pragma unroll
            for (int kd = 0; kd < 4; ++kd) {
                const bf16x8 bfr = *(const bf16x8*)&Kl[0][(jt * 4 + kd) * 512 + lane * 8];
                sc[jt] = __builtin_amdgcn_mfma_f32_16x16x32_bf16(qfrag[kd], bfr, sc[jt], 0, 0, 0);
            }
        if (nch > 1) {
            #pragma unroll
            for (int i = 0; i < 2; ++i) {
                const int seg = w * 2 + i;
                gload_lds16(Kpb + (size_t)(c0 + 1) * CHUNK_ELEMS + seg * 512 + lane * 8, &Kl[1][seg * 512]);
                gload_lds16(Vpb + (size_t)(c0 + 1) * CHUNK_ELEMS + seg * 512 + lane * 8, &Vl[1][seg * 512]);
            }
            #pragma unroll
            for (int jt = 0; jt < 4; ++jt)
                binit[jt] = bfrag[(size_t)(fb32 + c0 + 1) * 512 + jt];
        }

        for (int c = c0; c < cend; ++c) {
            const int cb = (c - c0) & 1;

            // ---- causal mask (diag chunk is 2T for waves 0-3, 2T+1 for 4-7;
            //      chunk 2T+1 is all-masked for waves 0-3 — mrun already finite
            //      because every slice containing 2T+1 also contains <=2T) ----
            if (c >= cdiag) {
                const int m0 = c * 64;
                #pragma unroll
                for (int jt = 0; jt < 4; ++jt)
                    #pragma unroll
                    for (int reg = 0; reg < 4; ++reg) {
                        const int gr = q0w + quad * 4 + reg;
                        const int gc = m0 + jt * 16 + l15;
                        if (gc > gr) sc[jt][reg] = -INFINITY;
                    }
            }

            // ---- online softmax; exact rescale-skip when no row max grows ----
            float mx[4];
            int grow = 0;
            #pragma unroll
            for (int reg = 0; reg < 4; ++reg) {
                float m = fmaxf(fmaxf(sc[0][reg], sc[1][reg]), fmaxf(sc[2][reg], sc[3][reg]));
                m = rmax16(m);
                mx[reg] = m;
                grow |= (m > mrun[reg]);
            }
            if (__any(grow)) {   // wave-uniform; skip path is numerically exact
                #pragma unroll
                for (int reg = 0; reg < 4; ++reg) {
                    const float mn = fmaxf(mrun[reg], mx[reg]);
                    const float alpha = __expf(mrun[reg] - mn);  // first chunk: exp(-inf)=0
                    mrun[reg] = mn;
                    lrun[reg] *= alpha;
                    #pragma unroll
                    for (int dt = 0; dt < 8; ++dt) oacc[dt][reg] *= alpha;
                }
            }
            #pragma unroll
            for (int reg = 0; reg < 4; ++reg) {
                float ls = 0.f;
                #pragma unroll
                for (int jt = 0; jt < 4; ++jt) {
                    const float pv = __expf(sc[jt][reg] - mrun[reg]);  // masked: exp(-inf)=0
                    sc[jt][reg] = pv;
                    ls += pv;
                }
                lrun[reg] += ls;   // per-lane partial; rsum16 deferred to epilogue
            }

            // ---- P: C-layout -> LDS (swizzled) -> A-layout ----
            #pragma unroll
            for (int jt = 0; jt < 4; ++jt)
                #pragma unroll
                for (int reg = 0; reg < 4; ++reg) {
                    const int row = quad * 4 + reg;
                    Pl[w][row][pswz(row, jt * 16 + l15)] = (__bf16)sc[jt][reg];
                }
            // same-wave write->read; compiler inserts lgkmcnt wait

            // ---- O += P V ----
            #pragma unroll
            for (int kj = 0; kj < 2; ++kj) {
                const bf16x8 pa = *(const bf16x8*)&Pl[w][l15][pswz(l15, kj * 32 + quad * 8)];
                #pragma unroll
                for (int dt = 0; dt < 8; ++dt) {
                    const bf16x8 vb = *(const bf16x8*)&Vl[cb][(kj * 8 + dt) * 512 + lane * 8];
                    oacc[dt] = __builtin_amdgcn_mfma_f32_16x16x32_bf16(pa, vb, oacc[dt], 0, 0, 0);
                }
            }

            // single barrier: all waves done reading Kl[cb]/Vl[cb]; vmcnt drain
            // covers DMA(c+1) (issued a full iteration ago -> near-free).
            __syncthreads();

            const bool n1 = (c + 1) < cend;
            const bool n2 = (c + 2) < cend;

            // ---- DMA chunk c+2 into buf[cb] (K(c)/V(c) both retired) ----
            if (n2) {
                const size_t off = (size_t)(c + 2) * CHUNK_ELEMS;
                #pragma unroll
                for (int i = 0; i < 2; ++i) {
                    const int seg = w * 2 + i;
                    gload_lds16(Kpb + off + seg * 512 + lane * 8, &Kl[cb][seg * 512]);
                    gload_lds16(Vpb + off + seg * 512 + lane * 8, &Vl[cb][seg * 512]);
                }
            }

            // ---- QK(c+1) from Kl[cb^1]; prefetched bias as C-init ----
            if (n1) {
                #pragma unroll
                for (int jt = 0; jt < 4; ++jt) sc[jt] = binit[jt];
                #pragma unroll
                for (int jt = 0; jt < 4; ++jt)
                    #pragma unroll
                    for (int kd = 0; kd < 4; ++kd) {
                        const bf16x8 bfr = *(const bf16x8*)&Kl[cb ^ 1][(jt * 4 + kd) * 512 + lane * 8];
                        sc[jt] = __builtin_amdgcn_mfma_f32_16x16x32_bf16(qfrag[kd], bfr, sc[jt], 0, 0, 0);
                    }
            }
            if (n2) {
                #pragma unroll
                for (int jt = 0; jt < 4; ++jt)
                    binit[jt] = bfrag[(size_t)(fb32 + c + 2) * 512 + jt];
            }
        }

        // ---- epilogue (deferred lrun row-reduction) ----
        if (direct) {
            #pragma unroll
            for (int reg = 0; reg < 4; ++reg) {
                const float inv = 1.0f / rsum16(lrun[reg]);
                const int gr = q0w + quad * 4 + reg;
                float* orow = out + ((size_t)b * Nc + gr) * Dc;
                #pragma unroll
                for (int dt = 0; dt < 8; ++dt)
                    orow[dt * 16 + l15] = oacc[dt][reg] * inv;
            }
        } else {
            float* pb = part + (size_t)(b * NPART8 + uid) * PART_FLOATS8;
            #pragma unroll
            for (int reg = 0; reg < 4; ++reg) {
                const int lr = w * 16 + quad * 4 + reg;
                #pragma unroll
                for (int dt = 0; dt < 8; ++dt)
                    pb[lr * 128 + dt * 16 + l15] = oacc[dt][reg];
                const float ls = rsum16(lrun[reg]);
                if (l15 == 0) {
                    pb[16384 + lr] = mrun[reg];
                    pb[16512 + lr] = ls;
                }
            }
        }
        // next unit's prologue DMA is safe: all Kl/Vl reads completed before
        // the final barrier of this unit's loop (epilogue is reg/global only).
    }
}

// ---- merge <=4 split partials per (b, 128-row tile T=2..15) ----
__global__ __launch_bounds__(256) void merge_parts8(
    const float* __restrict__ part, float* __restrict__ out)
{
    const int b = blockIdx.x;
    const int y = blockIdx.y;              // T = 2 + y
    const int T = 2 + y;
    const int S = MT_S[y];
    const int r  = threadIdx.x >> 1;       // row 0..127
    const int ch = threadIdx.x & 1;        // col half (64 cols)

    const float* pb[4];
    float m[4], a[4];
    float mstar = -INFINITY;
    #pragma unroll
    for (int s = 0; s < 4; ++s)
        if (s < S) {
            pb[s] = part + (size_t)(b * NPART8 + MT_U[y][s]) * PART_FLOATS8;
            m[s] = pb[s][16384 + r];
            mstar = fmaxf(mstar, m[s]);
        }
    float lsum = 0.f;
    #pragma unroll
    for (int s = 0; s < 4; ++s)
        if (s < S) {
            a[s] = __expf(m[s] - mstar);
            lsum += pb[s][16512 + r] * a[s];
        }
    const float inv = 1.0f / lsum;

    float* orow = out + ((size_t)b * Nc + T * 128 + r) * Dc + ch * 64;
    #pragma unroll
    for (int i = 0; i < 16; ++i) {
        float x = 0.f, yv = 0.f, z = 0.f, ww = 0.f;
        #pragma unroll
        for (int s = 0; s < 4; ++s)
            if (s < S) {
                const f32x4 v = *(const f32x4*)&pb[s][r * 128 + ch * 64 + i * 4];
                x += v[0] * a[s]; yv += v[1] * a[s]; z += v[2] * a[s]; ww += v[3] * a[s];
            }
        f32x4 o; o[0] = x * inv; o[1] = yv * inv; o[2] = z * inv; o[3] = ww * inv;
        *(f32x4*)&orow[i * 4] = o;
    }
}

// ---- legacy fallback (in-kernel staging, 4 bias reads) for tiny ws ----
__global__ __launch_bounds__(256) void attn_mfma_legacy(
    const float* __restrict__ Q, const float* __restrict__ K, const float* __restrict__ V,
    const float* __restrict__ p0, const float* __restrict__ p1,
    const float* __restrict__ p2, const float* __restrict__ p3,
    const int* __restrict__ imask, const int* __restrict__ emask,
    float* __restrict__ out)
{
    __shared__ __align__(16) __bf16 Klds[64][136];
    __shared__ __align__(16) __bf16 Vt[128][72];
    __shared__ __align__(16) __bf16 Plds[4][16][72];
    const int tid  = threadIdx.x;
    const int w    = tid >> 6;
    const int lane = tid & 63;
    const int quad = lane >> 4;
    const int l15  = lane & 15;
    const int b = blockIdx.y;
    const int x = blockIdx.x, yy = blockIdx.y;
    const int ti = (yy < 8) ? x : (31 - x);
    const int q0 = ti * 64, q0w = q0 + w * 16;
    const float* Qb = Q + (size_t)b * Nc * Dc;
    const float* Kb = K + (size_t)b * Nc * Dc;
    const float* Vb = V + (size_t)b * Nc * Dc;
    const int* imb = imask + b * Nc;

    bf16x8 qfrag[4];
    {
        const int row = q0w + l15;
        const float qs = emask[b * Nc + row] ? SCALE_F : 0.0f;
        const float4* qr = (const float4*)(Qb + (size_t)row * Dc);
        #pragma unroll
        for (int kd = 0; kd < 4; ++kd) {
            const float4 xv = qr[kd * 8 + quad * 2];
            const float4 yv = qr[kd * 8 + quad * 2 + 1];
            qfrag[kd][0]=(__bf16)(xv.x*qs); qfrag[kd][1]=(__bf16)(xv.y*qs);
            qfrag[kd][2]=(__bf16)(xv.z*qs); qfrag[kd][3]=(__bf16)(xv.w*qs);
            qfrag[kd][4]=(__bf16)(yv.x*qs); qfrag[kd][5]=(__bf16)(yv.y*qs);
            qfrag[kd][6]=(__bf16)(yv.z*qs); qfrag[kd][7]=(__bf16)(yv.w*qs);
        }
    }
    f32x4 oacc[8];
    #pragma unroll
    for (int dt = 0; dt < 8; ++dt){oacc[dt][0]=0.f;oacc[dt][1]=0.f;oacc[dt][2]=0.f;oacc[dt][3]=0.f;}
    float mrun[4]={-INFINITY,-INFINITY,-INFINITY,-INFINITY}, lrun[4]={0.f,0.f,0.f,0.f};

    for (int m0 = 0; m0 <= q0; m0 += 64) {
        __syncthreads();
        #pragma unroll
        for (int it = 0; it < 8; ++it) {
            const int idx = it * 256 + tid;
            const int row = idx >> 5, c4 = idx & 31;
            const int gm = m0 + row;
            const float msk = imb[gm] ? 1.0f : 0.0f;
            const float4 kf = ((const float4*)(Kb + (size_t)gm * Dc))[c4];
            const float4 vf = ((const float4*)(Vb + (size_t)gm * Dc))[c4];
            bf16x4 kb;
            kb[0]=(__bf16)(kf.x*msk); kb[1]=(__bf16)(kf.y*msk);
            kb[2]=(__bf16)(kf.z*msk); kb[3]=(__bf16)(kf.w*msk);
            *(bf16x4*)&Klds[row][c4*4] = kb;
            Vt[c4*4+0][row]=(__bf16)(vf.x*msk); Vt[c4*4+1][row]=(__bf16)(vf.y*msk);
            Vt[c4*4+2][row]=(__bf16)(vf.z*msk); Vt[c4*4+3][row]=(__bf16)(vf.w*msk);
        }
        __syncthreads();
        f32x4 sc[4];
        #pragma unroll
        for (int jt = 0; jt < 4; ++jt){sc[jt][0]=0.f;sc[jt][1]=0.f;sc[jt][2]=0.f;sc[jt][3]=0.f;}
        #pragma unroll
        for (int jt = 0; jt < 4; ++jt)
            #pragma unroll
            for (int kd = 0; kd < 4; ++kd) {
                const bf16x8 bfr = *(const bf16x8*)&Klds[jt*16+l15][kd*32+quad*8];
                sc[jt] = __builtin_amdgcn_mfma_f32_16x16x32_bf16(qfrag[kd], bfr, sc[jt], 0, 0, 0);
            }
        #pragma unroll
        for (int jt = 0; jt < 4; ++jt)
            #pragma unroll
            for (int reg = 0; reg < 4; ++reg) {
                const int gr = q0w + quad*4 + reg;
                const int gc = m0 + jt*16 + l15;
                const size_t boff = (size_t)gr * Nc + gc;
                const float bsx = p0[boff] + p1[boff] + p2[boff] + p3[boff];
                const float v = sc[jt][reg] + bsx;
                sc[jt][reg] = (gc > gr) ? -INFINITY : v;
            }
        #pragma unroll
        for (int reg = 0; reg < 4; ++reg) {
            float mx = fmaxf(fmaxf(sc[0][reg], sc[1][reg]), fmaxf(sc[2][reg], sc[3][reg]));
            mx = rmax16(mx);
            const float mn = fmaxf(mrun[reg], mx);
            const float alpha = __expf(mrun[reg] - mn);
            mrun[reg] = mn; lrun[reg] *= alpha;
            #pragma unroll
            for (int dt = 0; dt < 8; ++dt) oacc[dt][reg] *= alpha;
            float ls = 0.f;
            #pragma unroll
            for (int jt = 0; jt < 4; ++jt) {
                const float pv = __expf(sc[jt][reg] - mn);
                sc[jt][reg] = pv; ls += pv;
            }
            lrun[reg] += rsum16(ls);
        }
        #pragma unroll
        for (int jt = 0; jt < 4; ++jt)
            #pragma unroll
            for (int reg = 0; reg < 4; ++reg)
                Plds[w][quad*4+reg][jt*16+l15] = (__bf16)sc[jt][reg];
        #pragma unroll
        for (int kj = 0; kj < 2; ++kj) {
            const bf16x8 pa = *(const bf16x8*)&Plds[w][l15][kj*32+quad*8];
            #pragma unroll
            for (int dt = 0; dt < 8; ++dt) {
                const bf16x8 vb = *(const bf16x8*)&Vt[dt*16+l15][kj*32+quad*8];
                oacc[dt] = __builtin_amdgcn_mfma_f32_16x16x32_bf16(pa, vb, oacc[dt], 0, 0, 0);
            }
        }
    }
    #pragma unroll
    for (int reg = 0; reg < 4; ++reg) {
        const float inv = 1.0f / lrun[reg];
        const int gr = q0w + quad*4 + reg;
        float* orow = out + ((size_t)b * Nc + gr) * Dc;
        #pragma unroll
        for (int dt = 0; dt < 8; ++dt)
            orow[dt*16+l15] = oacc[dt][reg] * inv;
    }
}

extern "C" void kernel_launch(void* const* d_in, const int* in_sizes, int n_in,
                              void* d_out, int out_size, void* d_ws, size_t ws_size,
                              hipStream_t stream) {
    const float* Q  = (const float*)d_in[0];
    const float* K  = (const float*)d_in[1];
    const float* V  = (const float*)d_in[2];
    const float* b0 = (const float*)d_in[3];
    const float* b1 = (const float*)d_in[4];
    const float* b2 = (const float*)d_in[5];
    const float* b3 = (const float*)d_in[6];
    const int* im   = (const int*)d_in[7];
    const int* em   = (const int*)d_in[8];
    float* out      = (float*)d_out;

    const size_t need_full  = KPACK_BYTES + VPACK_BYTES + BIASP_BYTES;
    const size_t need_split = need_full + PART_BYTES8;

    if (ws_size >= need_full) {
        __bf16* Kp  = (__bf16*)d_ws;
        __bf16* Vp  = (__bf16*)((char*)d_ws + KPACK_BYTES);
        float*  bsp = (float*)((char*)d_ws + KPACK_BYTES + VPACK_BYTES);
        float*  prt = (float*)((char*)d_ws + need_full);
        prep_fused<<<512 + NUNITS, 256, 0, stream>>>(
            K, V, im, b0, b1, b2, b3, Kp, Vp, bsp);
        if (ws_size >= need_split) {
            attn8<true><<<dim3(Bc, 32), 512, 0, stream>>>(
                Q, Kp, Vp, bsp, em, out, prt);
            merge_parts8<<<dim3(Bc, 14), 256, 0, stream>>>(prt, out);
        } else {
            attn8<false><<<dim3(Bc, 16), 512, 0, stream>>>(
                Q, Kp, Vp, bsp, em, out, nullptr);
        }
    } else {
        attn_mfma_legacy<<<dim3(NCHUNK, Bc), 256, 0, stream>>>(
            Q, K, V, b0, b1, b2, b3, im, em, out);
    }
}